// Round 7
// baseline (120.407 us; speedup 1.0000x reference)
//
#include <hip/hip_runtime.h>

#define T_DIM 512
#define B_DIM 16
#define D_DIM 1024
#define WINR  16
#define NW    33                  // 2*WINR+1
#define TT    32                  // t-rows per attention block
#define NR    (TT + 2 * WINR)     // 64 source rows per block
#define DQ    256                 // d-columns per block (quarter of D)

typedef float f32x4 __attribute__((ext_vector_type(4)));

// ---------------- Kernel A: c[t,b] = dot(x[t,b,:], w_seq) ----------------
// One wave per (t,b) pair; 4 waves per block. Reads x exactly once (32 MiB).
__global__ __launch_bounds__(256) void calc_c_kernel(const float* __restrict__ x,
                                                     const float* __restrict__ w,
                                                     float* __restrict__ c) {
    const int wave = threadIdx.x >> 6;
    const int lane = threadIdx.x & 63;
    const int pair = blockIdx.x * 4 + wave;           // pair = t*B + b
    const f32x4* x4 = reinterpret_cast<const f32x4*>(x + (size_t)pair * D_DIM);
    const f32x4* w4 = reinterpret_cast<const f32x4*>(w + D_DIM);  // w_seq
    float acc = 0.f;
    #pragma unroll
    for (int i = 0; i < 4; ++i) {
        f32x4 xv = x4[i * 64 + lane];
        f32x4 wv = w4[i * 64 + lane];
        acc += xv.x * wv.x + xv.y * wv.y + xv.z * wv.z + xv.w * wv.w;
    }
    #pragma unroll
    for (int off = 32; off; off >>= 1) acc += __shfl_xor(acc, off, 64);
    if (lane == 0) c[pair] = acc;
}

// ------------- Kernel B: windowed softmax + gather + concat -------------
// Block = (b, 32 t-rows, 256-wide d-quarter). 256 threads, thread owns 1 float.
// acc[32] = 32 VGPRs -> no spill; grid 1024 blocks = 4/CU, 16 waves/CU.
// dd[i][j]: weight of source row (t0-16+i) for output row (t0+j); 0 outside window.
// (a[t,b] and bias are constant along the softmax axis -> cancel.)
__global__ __launch_bounds__(256) void attn_kernel(const float* __restrict__ x,
                                                   const float* __restrict__ c,
                                                   float* __restrict__ out) {
    __shared__ __align__(16) float dd[NR][TT];        // 8 KiB

    const int q   = blockIdx.x & 3;
    const int b   = (blockIdx.x >> 2) & (B_DIM - 1);
    const int t0  = (blockIdx.x >> 6) * TT;
    const int tid = threadIdx.x;
    const size_t rs  = (size_t)B_DIM * D_DIM;         // x t-stride (floats)
    const size_t ros = (size_t)B_DIM * 2 * D_DIM;     // out t-stride (floats)

    // ---- zero dd ----
    {
        float* ddf = &dd[0][0];
        #pragma unroll
        for (int i = 0; i < (NR * TT) / 256; ++i) ddf[tid + i * 256] = 0.f;
    }
    __syncthreads();

    // ---- phase 1: 32 threads compute softmax rows into diagonal layout ----
    if (tid < TT) {
        const int t = t0 + tid;
        float sc[NW];
        float m = -1e30f;
        #pragma unroll
        for (int ww = 0; ww < NW; ++ww) {
            const int s = t - WINR + ww;
            const float v = (s >= 0 && s < T_DIM) ? c[s * B_DIM + b] : -1e30f;
            sc[ww] = v;
            m = fmaxf(m, v);
        }
        float sum = 0.f;
        #pragma unroll
        for (int ww = 0; ww < NW; ++ww) {
            const float e = (sc[ww] > -1e29f) ? __expf(sc[ww] - m) : 0.f;
            sc[ww] = e;
            sum += e;
        }
        const float inv = 1.f / sum;
        #pragma unroll
        for (int ww = 0; ww < NW; ++ww) dd[tid + ww][tid] = sc[ww] * inv;
    }
    __syncthreads();

    // ---- phase 2: stream 64 source rows (each read once); prefetch next ----
    float acc[TT];
    #pragma unroll
    for (int j = 0; j < TT; ++j) acc[j] = 0.f;

    const float* xb = x + (size_t)b * D_DIM + q * DQ + tid;
    float* ob = out + (size_t)b * 2 * D_DIM + q * DQ + tid;

    auto loadrow = [&](int s) -> float {
        return ((unsigned)s < (unsigned)T_DIM) ? xb[(size_t)s * rs] : 0.f;
    };

    float xs = loadrow(t0 - WINR);
    #pragma unroll 2
    for (int ss = -WINR; ss < TT + WINR; ++ss) {
        const float xn = loadrow(t0 + ss + 1);        // prefetch (one-past ok)
        // center row doubles as the x-copy half of the output
        if ((unsigned)ss < (unsigned)TT) {
            ob[(size_t)(t0 + ss) * ros] = xs;
        }
        const f32x4* dr = reinterpret_cast<const f32x4*>(dd[ss + WINR]);

        #define FMA8(base, qq) \
            acc[base + 0] += (qq).x * xs; acc[base + 1] += (qq).y * xs; \
            acc[base + 2] += (qq).z * xs; acc[base + 3] += (qq).w * xs;
        {
            const f32x4 q0 = dr[0], q1 = dr[1], q2 = dr[2], q3 = dr[3];
            FMA8(0, q0) FMA8(4, q1) FMA8(8, q2) FMA8(12, q3)
        }
        {
            const f32x4 q4 = dr[4], q5 = dr[5], q6 = dr[6], q7 = dr[7];
            FMA8(16, q4) FMA8(20, q5) FMA8(24, q6) FMA8(28, q7)
        }
        #undef FMA8

        xs = xn;
    }

    // ---- phase 3: attention half ----
    #pragma unroll
    for (int j = 0; j < TT; ++j) {
        ob[(size_t)(t0 + j) * ros + D_DIM] = acc[j];
    }
}

extern "C" void kernel_launch(void* const* d_in, const int* in_sizes, int n_in,
                              void* d_out, int out_size, void* d_ws, size_t ws_size,
                              hipStream_t stream) {
    const float* x = (const float*)d_in[0];
    const float* w = (const float*)d_in[1];
    float* c   = (float*)d_ws;                 // T*B floats = 32 KiB scratch
    float* out = (float*)d_out;

    calc_c_kernel<<<(T_DIM * B_DIM) / 4, 256, 0, stream>>>(x, w, c);
    attn_kernel<<<(T_DIM / TT) * B_DIM * 4, 256, 0, stream>>>(x, c, out);
}

// Round 8
// 111.820 us; speedup vs baseline: 1.0768x; 1.0768x over previous
//
#include <hip/hip_runtime.h>

#define T_DIM 512
#define B_DIM 16
#define D_DIM 1024
#define WINR  16
#define NW    33                  // 2*WINR+1
#define TT    16                  // t-rows per attention block
#define NR    (TT + 2 * WINR)     // 48 source rows per block

typedef float f32x4 __attribute__((ext_vector_type(4)));

// ---------------- Kernel A: c[t,b] = dot(x[t,b,:], w_seq) ----------------
// One wave per (t,b) pair; 4 waves per block. Reads x exactly once (32 MiB).
__global__ __launch_bounds__(256) void calc_c_kernel(const float* __restrict__ x,
                                                     const float* __restrict__ w,
                                                     float* __restrict__ c) {
    const int wave = threadIdx.x >> 6;
    const int lane = threadIdx.x & 63;
    const int pair = blockIdx.x * 4 + wave;           // pair = t*B + b
    const f32x4* x4 = reinterpret_cast<const f32x4*>(x + (size_t)pair * D_DIM);
    const f32x4* w4 = reinterpret_cast<const f32x4*>(w + D_DIM);  // w_seq
    float acc = 0.f;
    #pragma unroll
    for (int i = 0; i < 4; ++i) {
        f32x4 xv = x4[i * 64 + lane];
        f32x4 wv = w4[i * 64 + lane];
        acc += xv.x * wv.x + xv.y * wv.y + xv.z * wv.z + xv.w * wv.w;
    }
    #pragma unroll
    for (int off = 32; off; off >>= 1) acc += __shfl_xor(acc, off, 64);
    if (lane == 0) c[pair] = acc;
}

// ------------- Kernel B: windowed softmax + gather + concat -------------
// Block = (b, 16 t-rows, FULL D). 256 threads, thread owns float4 at d=4*tid.
// acc = 16 x f32x4 = 64 VGPRs. 4-deep load ring hides HBM/L3 latency.
// dd[i][j]: weight of source row (t0-16+i) for output row (t0+j); 0 outside window.
// (a[t,b] and bias are constant along the softmax axis -> cancel.)
__global__ __launch_bounds__(256) void attn_kernel(const float* __restrict__ x,
                                                   const float* __restrict__ c,
                                                   float* __restrict__ out) {
    __shared__ __align__(16) float dd[NR][TT];        // 3 KiB

    const int b   = blockIdx.x & (B_DIM - 1);
    const int t0  = (blockIdx.x >> 4) * TT;
    const int tid = threadIdx.x;
    const size_t rs  = (size_t)B_DIM * D_DIM;         // x t-stride (floats)
    const size_t ros = (size_t)B_DIM * 2 * D_DIM;     // out t-stride (floats)

    // ---- zero dd ----
    {
        float* ddf = &dd[0][0];
        #pragma unroll
        for (int i = 0; i < (NR * TT) / 256; ++i) ddf[tid + i * 256] = 0.f;
    }
    __syncthreads();

    // ---- phase 1: 16 threads compute softmax rows into diagonal layout ----
    if (tid < TT) {
        const int t = t0 + tid;
        float sc[NW];
        float m = -1e30f;
        #pragma unroll
        for (int ww = 0; ww < NW; ++ww) {
            const int s = t - WINR + ww;
            const float v = (s >= 0 && s < T_DIM) ? c[s * B_DIM + b] : -1e30f;
            sc[ww] = v;
            m = fmaxf(m, v);
        }
        float sum = 0.f;
        #pragma unroll
        for (int ww = 0; ww < NW; ++ww) {
            const float e = (sc[ww] > -1e29f) ? __expf(sc[ww] - m) : 0.f;
            sc[ww] = e;
            sum += e;
        }
        const float inv = 1.f / sum;
        #pragma unroll
        for (int ww = 0; ww < NW; ++ww) dd[tid + ww][tid] = sc[ww] * inv;
    }
    __syncthreads();

    // ---- phase 2: stream 48 rows, 4-deep prefetch ring ----
    f32x4 acc[TT];
    #pragma unroll
    for (int j = 0; j < TT; ++j) acc[j] = (f32x4){0.f, 0.f, 0.f, 0.f};

    const float* xb = x + (size_t)b * D_DIM + (size_t)tid * 4;
    float* ob = out + (size_t)b * 2 * D_DIM + (size_t)tid * 4;

    auto loadrow = [&](int s) -> f32x4 {
        if ((unsigned)s < (unsigned)T_DIM)
            return *reinterpret_cast<const f32x4*>(xb + (size_t)s * rs);
        return (f32x4){0.f, 0.f, 0.f, 0.f};
    };

    f32x4 b0 = loadrow(t0 - WINR + 0);
    f32x4 b1 = loadrow(t0 - WINR + 1);
    f32x4 b2 = loadrow(t0 - WINR + 2);
    f32x4 b3 = loadrow(t0 - WINR + 3);

    #define PROCROW(ss, xv)                                                  \
    {                                                                        \
        if ((unsigned)(ss) < (unsigned)TT) {                                 \
            *reinterpret_cast<f32x4*>(ob + (size_t)(t0 + (ss)) * ros) = xv;  \
        }                                                                    \
        const f32x4* dr = reinterpret_cast<const f32x4*>(dd[(ss) + WINR]);   \
        const f32x4 q0 = dr[0], q1 = dr[1], q2 = dr[2], q3 = dr[3];          \
        acc[0]  += q0.x * xv; acc[1]  += q0.y * xv;                          \
        acc[2]  += q0.z * xv; acc[3]  += q0.w * xv;                          \
        acc[4]  += q1.x * xv; acc[5]  += q1.y * xv;                          \
        acc[6]  += q1.z * xv; acc[7]  += q1.w * xv;                          \
        acc[8]  += q2.x * xv; acc[9]  += q2.y * xv;                          \
        acc[10] += q2.z * xv; acc[11] += q2.w * xv;                          \
        acc[12] += q3.x * xv; acc[13] += q3.y * xv;                          \
        acc[14] += q3.z * xv; acc[15] += q3.w * xv;                          \
    }

    for (int base = -WINR; base < TT + WINR; base += 4) {
        // issue next 4 loads (one-past-end returns 0, harmless)
        f32x4 n0 = loadrow(t0 + base + 4);
        f32x4 n1 = loadrow(t0 + base + 5);
        f32x4 n2 = loadrow(t0 + base + 6);
        f32x4 n3 = loadrow(t0 + base + 7);
        PROCROW(base + 0, b0)
        PROCROW(base + 1, b1)
        PROCROW(base + 2, b2)
        PROCROW(base + 3, b3)
        b0 = n0; b1 = n1; b2 = n2; b3 = n3;
    }
    #undef PROCROW

    // ---- phase 3: attention half ----
    #pragma unroll
    for (int j = 0; j < TT; ++j) {
        *reinterpret_cast<f32x4*>(ob + (size_t)(t0 + j) * ros + D_DIM) = acc[j];
    }
}

extern "C" void kernel_launch(void* const* d_in, const int* in_sizes, int n_in,
                              void* d_out, int out_size, void* d_ws, size_t ws_size,
                              hipStream_t stream) {
    const float* x = (const float*)d_in[0];
    const float* w = (const float*)d_in[1];
    float* c   = (float*)d_ws;                 // T*B floats = 32 KiB scratch
    float* out = (float*)d_out;

    calc_c_kernel<<<(T_DIM * B_DIM) / 4, 256, 0, stream>>>(x, w, c);
    attn_kernel<<<(T_DIM / TT) * B_DIM, 256, 0, stream>>>(x, c, out);
}